// Round 6
// baseline (140.560 us; speedup 1.0000x reference)
//
#include <hip/hip_runtime.h>

// CoPE2d: B=64, NH=16, Wh=Ww=16, N=256, C=64, NPOS=288, BH=1024
// query (BH,256,64) f32; attn_logits (BH,256,256) f32; pos_emb (64,288) f32;
// out (BH,256,256) f32.
// One block per (bh, p): 16-row block, 256 threads (4 waves), 8 blocks/CU.
// LDS: single 16 KB buffer time-shared between gate logits (f32) and the
// bf16 L-table (GEMM output) -> 32 waves/CU residency.

#define NPOS 288
#define NT   18          // npos tiles of 16
#define LTS2 292         // bf16 Ltab row stride (u16 elements)

typedef __attribute__((ext_vector_type(8))) short bf16x8;
typedef __attribute__((ext_vector_type(4))) float f32x4;

__device__ __forceinline__ unsigned short f2bf(float f) {   // RNE f32->bf16
    unsigned u = __float_as_uint(f);
    u += 0x7FFF + ((u >> 16) & 1);
    return (unsigned short)(u >> 16);
}
__device__ __forceinline__ float bf2f(unsigned short b) {
    return __uint_as_float(((unsigned)b) << 16);
}

// dst[i] = src[i] + src[i+D] within 16-lane DPP rows, 0 beyond row end.
template <int D>
__device__ __forceinline__ float suffix_step(float v) {
    int s = __builtin_amdgcn_update_dpp(0, __float_as_int(v), 0x100 | D, 0xF, 0xF, true);
    return v + __int_as_float(s);
}

// async global->LDS, 16B per lane; lds dest = uniform base + lane*16
#define GLDS(gsrc, ldst) __builtin_amdgcn_global_load_lds(                      \
    (const __attribute__((address_space(1))) void*)(gsrc),                      \
    (__attribute__((address_space(3))) void*)(ldst), 16, 0, 0)

// ---- prep: pos_emb (64x288 f32) -> bf16 B-fragments in ws ------------------
__global__ void prep_kernel(const float* __restrict__ pos_emb,
                            short* __restrict__ wsb) {
    int idx = blockIdx.x * blockDim.x + threadIdx.x;   // 0 .. NT*2*64
    if (idx >= NT * 2 * 64) return;
    int l = idx & 63;
    int s = (idx >> 6) & 1;
    int t = idx >> 7;
    int col = t * 16 + (l & 15);
    int k0  = s * 32 + (l >> 4) * 8;
    short* dst = wsb + idx * 8;
    #pragma unroll
    for (int j = 0; j < 8; ++j)
        dst[j] = (short)f2bf(pos_emb[(k0 + j) * NPOS + col]);
}

__global__ __launch_bounds__(256, 8) void cope2d_kernel(
    const float* __restrict__ query,
    const float* __restrict__ attn_logits,
    const bf16x8* __restrict__ wsb8,
    float* __restrict__ out)
{
    __shared__ float smem[16 * 256];                 // 16384 B, time-shared
    float* Gl = smem;                                // phase 1: gate logits f32
    unsigned short* Lb = (unsigned short*)smem;      // phase 2: bf16 L-table

    const int tid  = threadIdx.x;
    const int lane = tid & 63;
    const int wave = tid >> 6;
    const int blk  = blockIdx.x;
    const int bh   = blk >> 4;
    const int p    = blk & 15;
    const long rowbase = (long)bh * 256 + p * 16;
    const long gbase   = rowbase * 256;

    // ---- 1: async DMA all 16 gate rows into LDS (no VGPRs held) ------------
    {
        const float* src = attn_logits + gbase + (long)(wave * 4) * 256 + lane * 4;
        float* dst = &Gl[(wave * 4) * 256];
        #pragma unroll
        for (int r = 0; r < 4; ++r)
            GLDS(src + r * 256, dst + r * 256);
    }

    // ---- 2: A fragments: q rows -> bf16 (row = lane&15, k = (lane>>4)*8+j) -
    const float* qptr = query + (rowbase + (lane & 15)) * 64 + (lane >> 4) * 8;
    bf16x8 A[2];
    #pragma unroll
    for (int s = 0; s < 2; ++s) {
        f32x4 lo = *(const f32x4*)(qptr + s * 32);
        f32x4 hi = *(const f32x4*)(qptr + s * 32 + 4);
        #pragma unroll
        for (int j = 0; j < 4; ++j) { A[s][j] = (short)f2bf(lo[j]); A[s][4 + j] = (short)f2bf(hi[j]); }
    }

    __syncthreads();   // #1: gate DMA drained (vmcnt 0), q in regs

    // ---- 3: pull gates to registers, sigmoid ------------------------------
    float g[16];
    #pragma unroll
    for (int i = 0; i < 16; ++i)
        g[i] = Gl[i * 256 + tid];                    // conflict-free ds_read
    #pragma unroll
    for (int i = 0; i < 16; ++i)
        g[i] = 1.0f / (1.0f + __expf(-g[i]));        // sigmoid

    __syncthreads();   // #2: WAR — all gate reads done before Lb overwrites

    // ---- 4: MFMA GEMM: Lb = bf16( q(16x64) @ P(64x288) ) -------------------
    for (int t = wave; t < NT; t += 4) {
        f32x4 c = {0.f, 0.f, 0.f, 0.f};
        c = __builtin_amdgcn_mfma_f32_16x16x32_bf16(A[0], wsb8[(t * 2 + 0) * 64 + lane], c, 0, 0, 0);
        c = __builtin_amdgcn_mfma_f32_16x16x32_bf16(A[1], wsb8[(t * 2 + 1) * 64 + lane], c, 0, 0, 0);
        const int col = t * 16 + (lane & 15);
        const int r0  = (lane >> 4) * 4;
        #pragma unroll
        for (int r = 0; r < 4; ++r)
            Lb[(r0 + r) * LTS2 + col] = f2bf(c[r]);
    }

    __syncthreads();   // #3: L-table complete

    // ---- 5: pos_h/pos_w -> gather+lerp -> out (batched) --------------------
    {
        float sfx[16];                               // pos_h suffix over rows
        float run = 0.f;
        #pragma unroll
        for (int i = 15; i >= 0; --i) { run += g[i]; sfx[i] = run; }

        #pragma unroll
        for (int half = 0; half < 2; ++half) {
            const int i0 = half * 8;
            float w8[8]; int fi8[8];
            #pragma unroll
            for (int k = 0; k < 8; ++k) {
                const int i = i0 + k;
                float pw = suffix_step<8>(suffix_step<4>(suffix_step<2>(suffix_step<1>(g[i]))));
                float pos = fminf(sfx[i] * 16.0f + pw, 287.0f);
                float pf = floorf(pos);
                fi8[k] = (int)pf;
                w8[k]  = pos - pf;
            }
            float lf8[8], lc8[8];
            #pragma unroll
            for (int k = 0; k < 8; ++k) {
                const unsigned short* Lr = Lb + (i0 + k) * LTS2;
                lf8[k] = bf2f(Lr[fi8[k]]);
                lc8[k] = bf2f(Lr[fi8[k] + 1]);
            }
            #pragma unroll
            for (int k = 0; k < 8; ++k)
                out[gbase + (long)(i0 + k) * 256 + tid] =
                    lf8[k] + w8[k] * (lc8[k] - lf8[k]);
        }
    }
}

extern "C" void kernel_launch(void* const* d_in, const int* in_sizes, int n_in,
                              void* d_out, int out_size, void* d_ws, size_t ws_size,
                              hipStream_t stream) {
    const float* query       = (const float*)d_in[0];
    const float* attn_logits = (const float*)d_in[1];
    const float* pos_emb     = (const float*)d_in[2];
    float* outp = (float*)d_out;
    short* wsb  = (short*)d_ws;          // NT*2*64*8 bf16 = 36 KB

    prep_kernel<<<9, 256, 0, stream>>>(pos_emb, wsb);
    cope2d_kernel<<<16384, 256, 0, stream>>>(query, attn_logits,
                                             (const bf16x8*)d_ws, outp);
}

// Round 7
// 139.884 us; speedup vs baseline: 1.0048x; 1.0048x over previous
//
#include <hip/hip_runtime.h>

// CoPE2d: B=64, NH=16, Wh=Ww=16, N=256, C=64, NPOS=288, BH=1024
// query (BH,256,64) f32; attn_logits (BH,256,256) f32; pos_emb (64,288) f32;
// out (BH,256,256) f32.
// One block = 4 consecutive 16-row blocks of one bh, software-pipelined:
// gates(s+1)/q(s+1) stream in under phaseD(s) + GEMM(s+1).
// 256 threads (4 waves). LDS = 9.4 KB bf16 L-table only.

#define NPOS 288
#define NT   18          // npos tiles of 16
#define LTS2 292         // bf16 Ltab row stride (u16 elements)

typedef __attribute__((ext_vector_type(8))) short bf16x8;
typedef __attribute__((ext_vector_type(4))) float f32x4;

__device__ __forceinline__ unsigned short f2bf(float f) {   // RNE f32->bf16
    unsigned u = __float_as_uint(f);
    u += 0x7FFF + ((u >> 16) & 1);
    return (unsigned short)(u >> 16);
}
__device__ __forceinline__ float bf2f(unsigned short b) {
    return __uint_as_float(((unsigned)b) << 16);
}

// dst[i] = src[i] + src[i+D] within 16-lane DPP rows, 0 beyond row end.
template <int D>
__device__ __forceinline__ float suffix_step(float v) {
    int s = __builtin_amdgcn_update_dpp(0, __float_as_int(v), 0x100 | D, 0xF, 0xF, true);
    return v + __int_as_float(s);
}

// ---- prep: pos_emb (64x288 f32) -> bf16 B-fragments in ws ------------------
__global__ void prep_kernel(const float* __restrict__ pos_emb,
                            short* __restrict__ wsb) {
    int idx = blockIdx.x * blockDim.x + threadIdx.x;   // 0 .. NT*2*64
    if (idx >= NT * 2 * 64) return;
    int l = idx & 63;
    int s = (idx >> 6) & 1;
    int t = idx >> 7;
    int col = t * 16 + (l & 15);
    int k0  = s * 32 + (l >> 4) * 8;
    short* dst = wsb + idx * 8;
    #pragma unroll
    for (int j = 0; j < 8; ++j)
        dst[j] = (short)f2bf(pos_emb[(k0 + j) * NPOS + col]);
}

__global__ __launch_bounds__(256, 4) void cope2d_kernel(
    const float* __restrict__ query,
    const float* __restrict__ attn_logits,
    const bf16x8* __restrict__ wsb8,
    float* __restrict__ out)
{
    __shared__ unsigned short Lb[16 * LTS2];   // 9344 B

    const int tid  = threadIdx.x;
    const int lane = tid & 63;
    const int wave = tid >> 6;
    const int blk  = blockIdx.x;               // 0..4095
    const int bh   = blk >> 2;
    const int p0   = (blk & 3) * 4;

    long rowbase = (long)bh * 256 + p0 * 16;
    long gb      = rowbase * 256;

    // ---- prologue: prefetch q + gates for step 0 ---------------------------
    const float* qp = query + (rowbase + (lane & 15)) * 64 + (lane >> 4) * 8;
    f32x4 q00 = *(const f32x4*)(qp);
    f32x4 q01 = *(const f32x4*)(qp + 4);
    f32x4 q10 = *(const f32x4*)(qp + 32);
    f32x4 q11 = *(const f32x4*)(qp + 36);
    float gn[16];
    #pragma unroll
    for (int i = 0; i < 16; ++i)
        gn[i] = attn_logits[gb + (long)i * 256 + tid];     // coalesced

    for (int s = 0; s < 4; ++s) {
        // ---- A fragments from prefetched q (row=lane&15, k=(lane>>4)*8+j) --
        bf16x8 A0, A1;
        #pragma unroll
        for (int j = 0; j < 4; ++j) {
            A0[j]     = (short)f2bf(q00[j]);
            A0[4 + j] = (short)f2bf(q01[j]);
            A1[j]     = (short)f2bf(q10[j]);
            A1[4 + j] = (short)f2bf(q11[j]);
        }

        if (s) __syncthreads();   // WAR: phaseD(s-1) gathers done before Lb overwrite

        // ---- MFMA GEMM -> Lb (bf16). B-loads' waits also drain gates(s). ---
        for (int t = wave; t < NT; t += 4) {
            f32x4 c = {0.f, 0.f, 0.f, 0.f};
            c = __builtin_amdgcn_mfma_f32_16x16x32_bf16(A0, wsb8[(t * 2 + 0) * 64 + lane], c, 0, 0, 0);
            c = __builtin_amdgcn_mfma_f32_16x16x32_bf16(A1, wsb8[(t * 2 + 1) * 64 + lane], c, 0, 0, 0);
            const int col = t * 16 + (lane & 15);
            const int r0  = (lane >> 4) * 4;
            #pragma unroll
            for (int r = 0; r < 4; ++r)
                Lb[(r0 + r) * LTS2 + col] = f2bf(c[r]);
        }

        // ---- sigmoid of current gates (already resident in steady state) ---
        float g[16];
        #pragma unroll
        for (int i = 0; i < 16; ++i)
            g[i] = 1.0f / (1.0f + __expf(-gn[i]));

        __syncthreads();          // Lb complete

        const long gbs = gb;      // out/gather base for this step

        // ---- prefetch q + gates for step s+1 (overlaps phaseD + next GEMM) -
        if (s < 3) {
            rowbase += 16;
            gb = rowbase * 256;
            const float* qp2 = query + (rowbase + (lane & 15)) * 64 + (lane >> 4) * 8;
            q00 = *(const f32x4*)(qp2);
            q01 = *(const f32x4*)(qp2 + 4);
            q10 = *(const f32x4*)(qp2 + 32);
            q11 = *(const f32x4*)(qp2 + 36);
            #pragma unroll
            for (int i = 0; i < 16; ++i)
                gn[i] = attn_logits[gb + (long)i * 256 + tid];
        }

        // ---- phase D: pos_h/pos_w -> gather+lerp -> out (rows 15..0) -------
        float run = 0.f;
        #pragma unroll
        for (int half = 1; half >= 0; --half) {
            const int i0 = half * 8;
            float r8[8];
            #pragma unroll
            for (int k = 7; k >= 0; --k) { run += g[i0 + k]; r8[k] = run; }

            float w8[8]; int fi8[8];
            #pragma unroll
            for (int k = 0; k < 8; ++k) {
                float pw = suffix_step<8>(suffix_step<4>(suffix_step<2>(suffix_step<1>(g[i0 + k]))));
                float pos = fminf(r8[k] * 16.0f + pw, 287.0f);
                float pf = floorf(pos);
                fi8[k] = (int)pf;
                w8[k]  = pos - pf;
            }
            float lf8[8], lc8[8];
            #pragma unroll
            for (int k = 0; k < 8; ++k) {
                const unsigned short* Lr = Lb + (i0 + k) * LTS2;
                lf8[k] = bf2f(Lr[fi8[k]]);
                lc8[k] = bf2f(Lr[fi8[k] + 1]);
            }
            #pragma unroll
            for (int k = 0; k < 8; ++k)
                out[gbs + (long)(i0 + k) * 256 + tid] =
                    lf8[k] + w8[k] * (lc8[k] - lf8[k]);
        }
    }
}

extern "C" void kernel_launch(void* const* d_in, const int* in_sizes, int n_in,
                              void* d_out, int out_size, void* d_ws, size_t ws_size,
                              hipStream_t stream) {
    const float* query       = (const float*)d_in[0];
    const float* attn_logits = (const float*)d_in[1];
    const float* pos_emb     = (const float*)d_in[2];
    float* outp = (float*)d_out;
    short* wsb  = (short*)d_ws;          // NT*2*64*8 bf16 = 36 KB

    prep_kernel<<<9, 256, 0, stream>>>(pos_emb, wsb);
    cope2d_kernel<<<4096, 256, 0, stream>>>(query, attn_logits,
                                            (const bf16x8*)d_ws, outp);
}